// Round 5
// baseline (2331.062 us; speedup 1.0000x reference)
//
#include <hip/hip_runtime.h>
#include <math.h>

#define B_ 4
#define N_ 1024
#define C_ 1024
#define H_ 16
#define HD_ 64

// ---------------------------------------------------------------------------
// ERROR MODEL (validated in r4, absmax 16 vs threshold 97):
//   S ~ 6.6e-6 at worst row; delta_S budget ~1.3e-7.
//   - V_m exact (f64 wsum collapse from x)        -> vall/wsum kernels
//   - pos+patch weights: f64 arg + exp to ~1e-9   -> fast_exp64 (3e-10 rel)
//   - q,k carry <1e-7 error                        -> slab-compensated GEMM
//   - PV numerators / stored q,k,v: f32 (damped by W_proj, budget 4e-3)
// ---------------------------------------------------------------------------

// fast f64 exp for |a| <= ~16: range-reduce + deg-8 Taylor. rel err ~3e-10.
__device__ __forceinline__ double fast_exp64(double a) {
    const double LOG2E = 1.4426950408889634074;
    const double LN2HI = 6.93147180369123816490e-01;
    const double LN2LO = 1.90821492927058770002e-10;
    const double MAGIC = 6755399441055744.0;   // 1.5 * 2^52
    double t     = a * LOG2E;
    double shift = t + MAGIC;
    int    n     = (int)__double_as_longlong(shift);   // low 32 bits = rint(t)
    double nd    = shift - MAGIC;
    double f     = __fma_rn(nd, -LN2HI, a);
    f            = __fma_rn(nd, -LN2LO, f);            // |f| <= 0.3466
    double p = 2.4801587301587301587e-05;              // 1/8!
    p = __fma_rn(p, f, 1.9841269841269841270e-04);     // 1/7!
    p = __fma_rn(p, f, 1.3888888888888888889e-03);     // 1/6!
    p = __fma_rn(p, f, 8.3333333333333333333e-03);     // 1/5!
    p = __fma_rn(p, f, 4.1666666666666666667e-02);     // 1/4!
    p = __fma_rn(p, f, 1.6666666666666666667e-01);     // 1/3!
    p = __fma_rn(p, f, 5.0e-01);
    p = __fma_rn(p, f, 1.0);
    p = __fma_rn(p, f, 1.0);
    return p * __longlong_as_double(((long long)(1023 + n)) << 52);
}

__device__ __forceinline__ void fma4(float4& acc, float s, const float4& v) {
    acc.x = fmaf(s, v.x, acc.x);
    acc.y = fmaf(s, v.y, acc.y);
    acc.z = fmaf(s, v.z, acc.z);
    acc.w = fmaf(s, v.w, acc.w);
}

// ---------------------------------------------------------------------------
// GEMM (unchanged from r4): slab-compensated f32->f64, tile 128x64.
// ---------------------------------------------------------------------------
template<int MODE>
__global__ __launch_bounds__(256)
void gemm_kernel(const float* __restrict__ A,
                 const float* __restrict__ W0,
                 const float* __restrict__ W1,
                 const float* __restrict__ bias,
                 float* __restrict__ out0,
                 float* __restrict__ out1,
                 float* __restrict__ out2,
                 int M, int O, int K)
{
    __shared__ float As[16][132];
    __shared__ float Ws[16][68];

    const int t  = threadIdx.x;
    const int m0 = blockIdx.y * 128;
    const int o0 = blockIdx.x * 64;
    const int ty = t >> 4;
    const int tx = t & 15;

    double acc[8][4];
    #pragma unroll
    for (int i = 0; i < 8; ++i)
        #pragma unroll
        for (int j = 0; j < 4; ++j) acc[i][j] = 0.0;

    for (int k0 = 0; k0 < K; k0 += 16) {
        #pragma unroll
        for (int i = 0; i < 2; ++i) {
            int vix = t + i * 256;
            int r   = vix >> 2;
            int c4  = vix & 3;
            const float4 a4 = *reinterpret_cast<const float4*>(&A[(size_t)(m0 + r) * K + k0 + c4 * 4]);
            As[c4 * 4 + 0][r] = a4.x;
            As[c4 * 4 + 1][r] = a4.y;
            As[c4 * 4 + 2][r] = a4.z;
            As[c4 * 4 + 3][r] = a4.w;
        }
        {
            int c  = t >> 2;
            int c4 = t & 3;
            int o  = o0 + c;
            const float* wrow = (MODE == 0 && o >= 2048) ? (W1 + (size_t)(o - 2048) * K)
                                                         : (W0 + (size_t)o * K);
            const float4 w4 = *reinterpret_cast<const float4*>(&wrow[k0 + c4 * 4]);
            Ws[c4 * 4 + 0][c] = w4.x;
            Ws[c4 * 4 + 1][c] = w4.y;
            Ws[c4 * 4 + 2][c] = w4.z;
            Ws[c4 * 4 + 3][c] = w4.w;
        }
        __syncthreads();

        float sacc[8][4];
        #pragma unroll
        for (int i = 0; i < 8; ++i)
            #pragma unroll
            for (int j = 0; j < 4; ++j) sacc[i][j] = 0.f;

        #pragma unroll
        for (int kk = 0; kk < 16; ++kk) {
            float a[8], bb[4];
            *reinterpret_cast<float4*>(&a[0])  = *reinterpret_cast<const float4*>(&As[kk][ty * 8]);
            *reinterpret_cast<float4*>(&a[4])  = *reinterpret_cast<const float4*>(&As[kk][ty * 8 + 4]);
            *reinterpret_cast<float4*>(&bb[0]) = *reinterpret_cast<const float4*>(&Ws[kk][tx * 4]);
            #pragma unroll
            for (int i = 0; i < 8; ++i)
                #pragma unroll
                for (int j = 0; j < 4; ++j)
                    sacc[i][j] += a[i] * bb[j];
        }
        #pragma unroll
        for (int i = 0; i < 8; ++i)
            #pragma unroll
            for (int j = 0; j < 4; ++j) acc[i][j] += (double)sacc[i][j];
        __syncthreads();
    }

    if (MODE == 1) {
        const float4 bsv = *reinterpret_cast<const float4*>(&bias[o0 + tx * 4]);
        #pragma unroll
        for (int i = 0; i < 8; ++i) {
            int m = m0 + ty * 8 + i;
            float4 r0 = make_float4((float)acc[i][0] + bsv.x, (float)acc[i][1] + bsv.y,
                                    (float)acc[i][2] + bsv.z, (float)acc[i][3] + bsv.w);
            *reinterpret_cast<float4*>(&out0[(size_t)m * O + o0 + tx * 4]) = r0;
        }
    } else {
        int oo = o0 + tx * 4;
        float* dst;
        if (oo < 2048) { dst = (oo < 1024) ? out0 : out1; oo &= 1023; }
        else           { dst = out2; oo -= 2048; }
        int hh = oo >> 6, d0 = oo & 63;
        #pragma unroll
        for (int i = 0; i < 8; ++i) {
            int m = m0 + ty * 8 + i;
            int bb_ = m >> 10, n = m & 1023;
            float4 r0 = make_float4((float)acc[i][0], (float)acc[i][1],
                                    (float)acc[i][2], (float)acc[i][3]);
            *reinterpret_cast<float4*>(&dst[((((size_t)bb_ * H_) + hh) * N_ + n) * HD_ + d0]) = r0;
        }
    }
}

// ---------------------------------------------------------------------------
__global__ void wsum_kernel(const float* __restrict__ W_v, double* __restrict__ wsh)
{
    const int k = blockIdx.x * 256 + threadIdx.x;
    const int h = blockIdx.y;
    double s = 0.0;
    #pragma unroll 8
    for (int d = 0; d < 64; ++d) s += (double)W_v[(size_t)(h * 64 + d) * C_ + k];
    wsh[h * C_ + k] = s;
}

__global__ __launch_bounds__(256)
void vall_kernel(const float* __restrict__ x, const double* __restrict__ wsh,
                 double* __restrict__ Vall)
{
    __shared__ double ws_s[1024];
    const int h = blockIdx.y, b = blockIdx.z;
    const int m = blockIdx.x * 256 + threadIdx.x;
    for (int i = threadIdx.x; i < 1024; i += 256) ws_s[i] = wsh[h * C_ + i];
    __syncthreads();
    const float* xr = x + ((size_t)b * N_ + m) * C_;
    double acc = 0.0;
    #pragma unroll 8
    for (int kk = 0; kk < 1024; ++kk) acc += (double)xr[kk] * ws_s[kk];
    Vall[((size_t)b * H_ + h) * N_ + m] = acc;
}

// ---------------------------------------------------------------------------
// Fused attention, restructured (r5):
//  - K and V read straight from global (tiles are 16KB, L1/L2-served;
//    staging them in LDS was 33KB + 3 barriers/tile of pure overhead).
//  - pt/qt are wave-private rows -> NO barriers in the main loop.
//  - PV remap: lane = (m-quarter g = l>>4, dims 4*(l&15)..+3); per-group
//    partials in registers, one shfl-reduce at the epilogue.
//  - f64 exp via fast_exp64 (rel err 3e-10, well under S budget).
//  - LDS 45.5KB -> 12.4KB => 4 blocks/CU (launch_bounds(256,4)).
// ---------------------------------------------------------------------------
__global__ __launch_bounds__(256, 4)
void attn_kernel(const float* __restrict__ q,
                 const float* __restrict__ k,
                 const float* __restrict__ v,
                 const double* __restrict__ Vall,   // [B][H][N]
                 const float* __restrict__ coord,   // [B][N][3]
                 const float* __restrict__ W_pos,   // [H][4]
                 const float* __restrict__ gating,  // [H]
                 float* __restrict__ attn_out)      // [B][N][C]
{
    __shared__ float4 Qs4[16][16];                 // q rows [r][d4]
    __shared__ __align__(16) float pt[16][64];     // patch weights (wave-private rows)
    __shared__ __align__(16) float qt[16][64];     // pos weights (wave-private rows)
    __shared__ float qc[16][3];

    const int t  = threadIdx.x;
    const int w  = t >> 6;     // wave 0..3, owns rows {w, w+4, w+8, w+12}
    const int l  = t & 63;     // lane
    const int g  = l >> 4;     // m-quarter for PV
    const int dl = l & 15;     // dim group for PV (dims 4*dl..4*dl+3)
    const int n0 = blockIdx.x * 16;
    const int h  = blockIdx.y;
    const int b  = blockIdx.z;
    const size_t bhN = ((size_t)b * H_ + h) * N_;

    const float* qbase = q + (bhN + n0) * HD_;
    Qs4[t >> 4][t & 15] = reinterpret_cast<const float4*>(qbase)[t];
    if (t < 48) qc[t / 3][t % 3] = coord[((size_t)b * N_ + n0 + t / 3) * 3 + (t % 3)];
    const double w4hd = (double)W_pos[h * 4 + 3];
    const double ghd  = 1.0 / (1.0 + exp(-(double)gating[h]));
    __syncthreads();   // Qs4/qc ready; ONLY barrier in the kernel

    // f64 S-path accumulators (lane = key m); f32 PV partials (lane = (g,dl))
    double sp[4], sq[4], spv[4], sqv[4];
    float4 accp4[4], accq4[4];
    #pragma unroll
    for (int i = 0; i < 4; ++i) {
        sp[i] = 0.0; sq[i] = 0.0; spv[i] = 0.0; sqv[i] = 0.0;
        accp4[i] = make_float4(0.f, 0.f, 0.f, 0.f);
        accq4[i] = make_float4(0.f, 0.f, 0.f, 0.f);
    }

    for (int m0 = 0; m0 < N_; m0 += 64) {
        // ---- QK^T logits from global K (L1-served): rows w+4i, column m0+l
        const float4* krow = reinterpret_cast<const float4*>(k + (bhN + m0 + l) * HD_);
        float dotp[4][4];
        #pragma unroll
        for (int i = 0; i < 4; ++i)
            #pragma unroll
            for (int c = 0; c < 4; ++c) dotp[i][c] = 0.f;
        #pragma unroll
        for (int d4c = 0; d4c < 4; ++d4c) {
            float4 kt0 = krow[d4c * 4 + 0];
            float4 kt1 = krow[d4c * 4 + 1];
            float4 kt2 = krow[d4c * 4 + 2];
            float4 kt3 = krow[d4c * 4 + 3];
            #pragma unroll
            for (int i = 0; i < 4; ++i) {
                const float4 q0 = Qs4[w + 4 * i][d4c * 4 + 0];
                const float4 q1 = Qs4[w + 4 * i][d4c * 4 + 1];
                const float4 q2 = Qs4[w + 4 * i][d4c * 4 + 2];
                const float4 q3 = Qs4[w + 4 * i][d4c * 4 + 3];
                float s = dotp[i][d4c];
                s = fmaf(kt0.x, q0.x, s); s = fmaf(kt0.y, q0.y, s);
                s = fmaf(kt0.z, q0.z, s); s = fmaf(kt0.w, q0.w, s);
                s = fmaf(kt1.x, q1.x, s); s = fmaf(kt1.y, q1.y, s);
                s = fmaf(kt1.z, q1.z, s); s = fmaf(kt1.w, q1.w, s);
                s = fmaf(kt2.x, q2.x, s); s = fmaf(kt2.y, q2.y, s);
                s = fmaf(kt2.z, q2.z, s); s = fmaf(kt2.w, q2.w, s);
                s = fmaf(kt3.x, q3.x, s); s = fmaf(kt3.y, q3.y, s);
                s = fmaf(kt3.z, q3.z, s); s = fmaf(kt3.w, q3.w, s);
                dotp[i][d4c] = s;
            }
        }

        // ---- weights + f64 S-path updates (lane = m = m0+l)
        const double Vm  = Vall[bhN + m0 + l];
        const double cmx = (double)coord[((size_t)b * N_ + m0 + l) * 3 + 0];
        const double cmy = (double)coord[((size_t)b * N_ + m0 + l) * 3 + 1];
        const double cmz = (double)coord[((size_t)b * N_ + m0 + l) * 3 + 2];
        #pragma unroll
        for (int i = 0; i < 4; ++i) {
            const int r = w + 4 * i;
            const double lg = (((double)dotp[i][0] + (double)dotp[i][1]) +
                               ((double)dotp[i][2] + (double)dotp[i][3])) * 0.125;
            const double p64 = fast_exp64(lg);
            const double dx = (double)qc[r][0] - cmx;
            const double dy = (double)qc[r][1] - cmy;
            const double dz = (double)qc[r][2] - cmz;
            const double r2 = __fma_rn(dx, dx, __fma_rn(dy, dy, dz * dz));
            const double y0 = (double)rsqrtf((float)r2);
            const double y1 = y0 * __fma_rn(-0.5 * r2, y0 * y0, 1.5);
            const double dist = (r2 > 0.0) ? r2 * y1 : 0.0;   // sqrt via rsqrt-NR
            const double q64 = fast_exp64(dist * w4hd);
            pt[r][l] = (float)p64;
            qt[r][l] = (float)q64;
            sp[i]  += p64;
            sq[i]  += q64;
            spv[i] += p64 * Vm;
            sqv[i] += q64 * Vm;
        }
        // pt/qt rows are written and read by the SAME wave -> in-order LDS
        // per wave + compiler lgkmcnt waits give correctness without a barrier.

        // ---- PV from global V: lane covers m in [g*16, g*16+16), dims 4dl..+3
        const float4* vrow = reinterpret_cast<const float4*>(v + (bhN + m0 + g * 16) * HD_) + dl;
        #pragma unroll
        for (int mc = 0; mc < 4; ++mc) {
            const float4 vr0 = vrow[(mc * 4 + 0) * 16];
            const float4 vr1 = vrow[(mc * 4 + 1) * 16];
            const float4 vr2 = vrow[(mc * 4 + 2) * 16];
            const float4 vr3 = vrow[(mc * 4 + 3) * 16];
            #pragma unroll
            for (int i = 0; i < 4; ++i) {
                const float4 pp = *reinterpret_cast<const float4*>(&pt[w + 4 * i][g * 16 + mc * 4]);
                const float4 pq = *reinterpret_cast<const float4*>(&qt[w + 4 * i][g * 16 + mc * 4]);
                fma4(accp4[i], pp.x, vr0); fma4(accp4[i], pp.y, vr1);
                fma4(accp4[i], pp.z, vr2); fma4(accp4[i], pp.w, vr3);
                fma4(accq4[i], pq.x, vr0); fma4(accq4[i], pq.y, vr1);
                fma4(accq4[i], pq.z, vr2); fma4(accq4[i], pq.w, vr3);
            }
        }
    }

    // ---- epilogue ----
    // 1) complete PV sums across the 4 m-quarters (lanes xor 16, 32)
    #pragma unroll
    for (int i = 0; i < 4; ++i) {
        #pragma unroll
        for (int mask = 16; mask <= 32; mask <<= 1) {
            accp4[i].x += __shfl_xor(accp4[i].x, mask);
            accp4[i].y += __shfl_xor(accp4[i].y, mask);
            accp4[i].z += __shfl_xor(accp4[i].z, mask);
            accp4[i].w += __shfl_xor(accp4[i].w, mask);
            accq4[i].x += __shfl_xor(accq4[i].x, mask);
            accq4[i].y += __shfl_xor(accq4[i].y, mask);
            accq4[i].z += __shfl_xor(accq4[i].z, mask);
            accq4[i].w += __shfl_xor(accq4[i].w, mask);
        }
    }
    // 2) f64 reduce of S-path sums across all 64 lanes; per-row scalars
    double w1a[4], w2a[4], Sa[4];
    #pragma unroll
    for (int i = 0; i < 4; ++i) {
        double vsp = sp[i], vsq = sq[i], vspv = spv[i], vsqv = sqv[i];
        #pragma unroll
        for (int mm = 32; mm >= 1; mm >>= 1) {
            vsp  += __shfl_xor(vsp,  mm);
            vsq  += __shfl_xor(vsq,  mm);
            vspv += __shfl_xor(vspv, mm);
            vsqv += __shfl_xor(vsqv, mm);
        }
        w1a[i] = (1.0 - ghd) / vsp;
        w2a[i] = ghd / vsq;
        Sa[i]  = w1a[i] * vspv + w2a[i] * vsqv;
    }
    // 3) lane (g, dl) stores row w+4g, dims 4dl..4dl+3
    float4 ap = accp4[0], aq = accq4[0];
    double w1g = w1a[0], w2g = w2a[0], Sg = Sa[0];
    if (g == 1) { ap = accp4[1]; aq = accq4[1]; w1g = w1a[1]; w2g = w2a[1]; Sg = Sa[1]; }
    if (g == 2) { ap = accp4[2]; aq = accq4[2]; w1g = w1a[2]; w2g = w2a[2]; Sg = Sa[2]; }
    if (g == 3) { ap = accp4[3]; aq = accq4[3]; w1g = w1a[3]; w2g = w2a[3]; Sg = Sa[3]; }
    const double inv = 1.0 / Sg;
    float4 o;
    o.x = (float)((w1g * (double)ap.x + w2g * (double)aq.x) * inv);
    o.y = (float)((w1g * (double)ap.y + w2g * (double)aq.y) * inv);
    o.z = (float)((w1g * (double)ap.z + w2g * (double)aq.z) * inv);
    o.w = (float)((w1g * (double)ap.w + w2g * (double)aq.w) * inv);
    *reinterpret_cast<float4*>(&attn_out[((size_t)b * N_ + n0 + w + 4 * g) * C_ + h * HD_ + 4 * dl]) = o;
}

// ---------------------------------------------------------------------------
extern "C" void kernel_launch(void* const* d_in, const int* in_sizes, int n_in,
                              void* d_out, int out_size, void* d_ws, size_t ws_size,
                              hipStream_t stream)
{
    const float* x      = (const float*)d_in[0];
    const float* coord  = (const float*)d_in[1];
    const float* W_qk   = (const float*)d_in[2];
    const float* W_v    = (const float*)d_in[3];
    const float* W_proj = (const float*)d_in[4];
    const float* b_proj = (const float*)d_in[5];
    const float* W_pos  = (const float*)d_in[6];
    // d_in[7] = b_pos (cancels in softmax), d_in[9] = pos_emb (cancels) — unused
    const float* gating = (const float*)d_in[8];

    float* ws   = (float*)d_ws;
    const size_t per = (size_t)B_ * H_ * N_ * HD_;   // 4,194,304 floats
    float*  qb   = ws;
    float*  kb   = qb + per;
    float*  vb   = kb + per;
    float*  attn = vb + per;
    double* wsh  = (double*)(attn + per);
    double* Vall = wsh + (size_t)H_ * C_;
    float*  out  = (float*)d_out;

    wsum_kernel<<<dim3(4, 16), 256, 0, stream>>>(W_v, wsh);
    vall_kernel<<<dim3(4, 16, 4), 256, 0, stream>>>(x, wsh, Vall);

    gemm_kernel<0><<<dim3(48, 32), 256, 0, stream>>>(
        x, W_qk, W_v, nullptr, qb, kb, vb, B_ * N_, 3 * C_, C_);

    attn_kernel<<<dim3(N_ / 16, H_, B_), 256, 0, stream>>>(
        qb, kb, vb, Vall, coord, W_pos, gating, attn);

    gemm_kernel<1><<<dim3(16, 32), 256, 0, stream>>>(
        attn, W_proj, nullptr, b_proj, out, nullptr, nullptr, B_ * N_, C_, C_);
}

// Round 6
// 1577.649 us; speedup vs baseline: 1.4776x; 1.4776x over previous
//
#include <hip/hip_runtime.h>
#include <math.h>

#define B_ 4
#define N_ 1024
#define C_ 1024
#define H_ 16
#define HD_ 64

// ---------------------------------------------------------------------------
// ERROR MODEL (validated r4: absmax 16 vs threshold 97):
//   S ~ 6.6e-6 worst row; delta_S budget ~1.3e-7 (1/S amplification).
//   - V_m exact (f64 wsum collapse from x)       -> wsum/vall kernels
//   - pos+patch weights f64 arg + exp ~1e-9 rel  -> fast_exp64 (3e-10),
//     sqrt via rsqrtf+NR (9e-14 rel)
//   - q,k carry <1e-7                            -> slab-compensated GEMM
//   - PV numerators / stored q,k,v: f32 (damped by W_proj, budget 4e-3)
// PERF MODEL (r5 lesson): keep register footprint <= ~128 (r5's restructure
// spilled: VGPR 56 + 8.5GB scratch writes). r4 structure + fast_exp64 +
// V-from-global + wave-private pt/qt (2 barriers/tile).
// ---------------------------------------------------------------------------

// fast f64 exp for |a| <= ~16: range-reduce + deg-8 Taylor. rel err ~3e-10.
__device__ __forceinline__ double fast_exp64(double a) {
    const double LOG2E = 1.4426950408889634074;
    const double LN2HI = 6.93147180369123816490e-01;
    const double LN2LO = 1.90821492927058770002e-10;
    const double MAGIC = 6755399441055744.0;   // 1.5 * 2^52
    double t     = a * LOG2E;
    double shift = t + MAGIC;
    int    n     = (int)__double_as_longlong(shift);   // low 32 = rint(t)
    double nd    = shift - MAGIC;
    double f     = __fma_rn(nd, -LN2HI, a);
    f            = __fma_rn(nd, -LN2LO, f);            // |f| <= 0.3466
    double p = 2.4801587301587301587e-05;
    p = __fma_rn(p, f, 1.9841269841269841270e-04);
    p = __fma_rn(p, f, 1.3888888888888888889e-03);
    p = __fma_rn(p, f, 8.3333333333333333333e-03);
    p = __fma_rn(p, f, 4.1666666666666666667e-02);
    p = __fma_rn(p, f, 1.6666666666666666667e-01);
    p = __fma_rn(p, f, 5.0e-01);
    p = __fma_rn(p, f, 1.0);
    p = __fma_rn(p, f, 1.0);
    return p * __longlong_as_double(((long long)(1023 + n)) << 52);
}

// ---------------------------------------------------------------------------
// GEMM (unchanged, known-good): slab-compensated f32->f64, tile 128x64.
// ---------------------------------------------------------------------------
template<int MODE>
__global__ __launch_bounds__(256)
void gemm_kernel(const float* __restrict__ A,
                 const float* __restrict__ W0,
                 const float* __restrict__ W1,
                 const float* __restrict__ bias,
                 float* __restrict__ out0,
                 float* __restrict__ out1,
                 float* __restrict__ out2,
                 int M, int O, int K)
{
    __shared__ float As[16][132];
    __shared__ float Ws[16][68];

    const int t  = threadIdx.x;
    const int m0 = blockIdx.y * 128;
    const int o0 = blockIdx.x * 64;
    const int ty = t >> 4;
    const int tx = t & 15;

    double acc[8][4];
    #pragma unroll
    for (int i = 0; i < 8; ++i)
        #pragma unroll
        for (int j = 0; j < 4; ++j) acc[i][j] = 0.0;

    for (int k0 = 0; k0 < K; k0 += 16) {
        #pragma unroll
        for (int i = 0; i < 2; ++i) {
            int vix = t + i * 256;
            int r   = vix >> 2;
            int c4  = vix & 3;
            const float4 a4 = *reinterpret_cast<const float4*>(&A[(size_t)(m0 + r) * K + k0 + c4 * 4]);
            As[c4 * 4 + 0][r] = a4.x;
            As[c4 * 4 + 1][r] = a4.y;
            As[c4 * 4 + 2][r] = a4.z;
            As[c4 * 4 + 3][r] = a4.w;
        }
        {
            int c  = t >> 2;
            int c4 = t & 3;
            int o  = o0 + c;
            const float* wrow = (MODE == 0 && o >= 2048) ? (W1 + (size_t)(o - 2048) * K)
                                                         : (W0 + (size_t)o * K);
            const float4 w4 = *reinterpret_cast<const float4*>(&wrow[k0 + c4 * 4]);
            Ws[c4 * 4 + 0][c] = w4.x;
            Ws[c4 * 4 + 1][c] = w4.y;
            Ws[c4 * 4 + 2][c] = w4.z;
            Ws[c4 * 4 + 3][c] = w4.w;
        }
        __syncthreads();

        float sacc[8][4];
        #pragma unroll
        for (int i = 0; i < 8; ++i)
            #pragma unroll
            for (int j = 0; j < 4; ++j) sacc[i][j] = 0.f;

        #pragma unroll
        for (int kk = 0; kk < 16; ++kk) {
            float a[8], bb[4];
            *reinterpret_cast<float4*>(&a[0])  = *reinterpret_cast<const float4*>(&As[kk][ty * 8]);
            *reinterpret_cast<float4*>(&a[4])  = *reinterpret_cast<const float4*>(&As[kk][ty * 8 + 4]);
            *reinterpret_cast<float4*>(&bb[0]) = *reinterpret_cast<const float4*>(&Ws[kk][tx * 4]);
            #pragma unroll
            for (int i = 0; i < 8; ++i)
                #pragma unroll
                for (int j = 0; j < 4; ++j)
                    sacc[i][j] += a[i] * bb[j];
        }
        #pragma unroll
        for (int i = 0; i < 8; ++i)
            #pragma unroll
            for (int j = 0; j < 4; ++j) acc[i][j] += (double)sacc[i][j];
        __syncthreads();
    }

    if (MODE == 1) {
        const float4 bsv = *reinterpret_cast<const float4*>(&bias[o0 + tx * 4]);
        #pragma unroll
        for (int i = 0; i < 8; ++i) {
            int m = m0 + ty * 8 + i;
            float4 r0 = make_float4((float)acc[i][0] + bsv.x, (float)acc[i][1] + bsv.y,
                                    (float)acc[i][2] + bsv.z, (float)acc[i][3] + bsv.w);
            *reinterpret_cast<float4*>(&out0[(size_t)m * O + o0 + tx * 4]) = r0;
        }
    } else {
        int oo = o0 + tx * 4;
        float* dst;
        if (oo < 2048) { dst = (oo < 1024) ? out0 : out1; oo &= 1023; }
        else           { dst = out2; oo -= 2048; }
        int hh = oo >> 6, d0 = oo & 63;
        #pragma unroll
        for (int i = 0; i < 8; ++i) {
            int m = m0 + ty * 8 + i;
            int bb_ = m >> 10, n = m & 1023;
            float4 r0 = make_float4((float)acc[i][0], (float)acc[i][1],
                                    (float)acc[i][2], (float)acc[i][3]);
            *reinterpret_cast<float4*>(&dst[((((size_t)bb_ * H_) + hh) * N_ + n) * HD_ + d0]) = r0;
        }
    }
}

// ---------------------------------------------------------------------------
__global__ void wsum_kernel(const float* __restrict__ W_v, double* __restrict__ wsh)
{
    const int k = blockIdx.x * 256 + threadIdx.x;
    const int h = blockIdx.y;
    double s = 0.0;
    #pragma unroll 8
    for (int d = 0; d < 64; ++d) s += (double)W_v[(size_t)(h * 64 + d) * C_ + k];
    wsh[h * C_ + k] = s;
}

__global__ __launch_bounds__(256)
void vall_kernel(const float* __restrict__ x, const double* __restrict__ wsh,
                 double* __restrict__ Vall)
{
    __shared__ double ws_s[1024];
    const int h = blockIdx.y, b = blockIdx.z;
    const int m = blockIdx.x * 256 + threadIdx.x;
    for (int i = threadIdx.x; i < 1024; i += 256) ws_s[i] = wsh[h * C_ + i];
    __syncthreads();
    const float* xr = x + ((size_t)b * N_ + m) * C_;
    double acc = 0.0;
    #pragma unroll 8
    for (int kk = 0; kk < 1024; ++kk) acc += (double)xr[kk] * ws_s[kk];
    Vall[((size_t)b * H_ + h) * N_ + m] = acc;
}

// ---------------------------------------------------------------------------
// Fused attention (r6 = r4 structure + targeted wins):
//  - K staged in swizzled LDS (per-lane-row access is bad from global).
//  - V read DIRECT from global in PV (per-m coalesced 256B, L1-served).
//  - pt/qt wave-private rows -> no barrier between weights and PV;
//    exactly 2 barriers/tile (both protecting Kt4).
//  - fast_exp64 + rsqrt-NR f64 sqrt.
//  - PV accumulators: 8 scalar f32 regs (lane = output dim), r4 mapping.
// ---------------------------------------------------------------------------
__global__ __launch_bounds__(256)
void attn_kernel(const float* __restrict__ q,
                 const float* __restrict__ k,
                 const float* __restrict__ v,
                 const double* __restrict__ Vall,   // [B][H][N]
                 const float* __restrict__ coord,   // [B][N][3]
                 const float* __restrict__ W_pos,   // [H][4]
                 const float* __restrict__ gating,  // [H]
                 float* __restrict__ attn_out)      // [B][N][C]
{
    __shared__ float4 Qs4[16][16];                 // 4KB q rows
    __shared__ float4 Kt4[64][16];                 // 16KB swizzled K tile
    __shared__ __align__(16) float pt[16][64];     // 4KB patch weights (wave-private rows)
    __shared__ __align__(16) float qt[16][64];     // 4KB pos weights
    __shared__ float qc[16][3];

    const int t  = threadIdx.x;
    const int w  = t >> 6;     // wave 0..3, owns rows {w, w+4, w+8, w+12}
    const int l  = t & 63;     // lane
    const int n0 = blockIdx.x * 16;
    const int h  = blockIdx.y;
    const int b  = blockIdx.z;
    const size_t bhN = ((size_t)b * H_ + h) * N_;

    const float* qbase = q + (bhN + n0) * HD_;
    Qs4[t >> 4][t & 15] = reinterpret_cast<const float4*>(qbase)[t];
    if (t < 48) qc[t / 3][t % 3] = coord[((size_t)b * N_ + n0 + t / 3) * 3 + (t % 3)];
    const double w4hd = (double)W_pos[h * 4 + 3];
    const double ghd  = 1.0 / (1.0 + exp(-(double)gating[h]));

    double sp[4], sq[4], spv[4], sqv[4];
    float accp[4], accq[4];
    #pragma unroll
    for (int i = 0; i < 4; ++i) {
        sp[i] = 0.0; sq[i] = 0.0; spv[i] = 0.0; sqv[i] = 0.0;
        accp[i] = 0.f; accq[i] = 0.f;
    }
    __syncthreads();   // Qs4/qc ready

    for (int m0 = 0; m0 < N_; m0 += 64) {
        // ---- stage K tile (coalesced global -> swizzled LDS)
        const float4* kb4 = reinterpret_cast<const float4*>(k + (bhN + m0) * HD_);
        #pragma unroll
        for (int i = 0; i < 4; ++i) {
            int vix = t + i * 256;
            int r   = vix >> 4;   // 0..63
            int c4  = vix & 15;
            Kt4[r][c4 ^ (r & 15)] = kb4[vix];
        }
        // per-lane S-path inputs (global, coalesced)
        const double Vm  = Vall[bhN + m0 + l];
        const double cmx = (double)coord[((size_t)b * N_ + m0 + l) * 3 + 0];
        const double cmy = (double)coord[((size_t)b * N_ + m0 + l) * 3 + 1];
        const double cmz = (double)coord[((size_t)b * N_ + m0 + l) * 3 + 2];
        __syncthreads();   // Kt4 ready

        // ---- QK^T logits from LDS: rows w+4i, column m0+l (split partials)
        float dotp[4][4];
        #pragma unroll
        for (int i = 0; i < 4; ++i)
            #pragma unroll
            for (int g = 0; g < 4; ++g) dotp[i][g] = 0.f;
        #pragma unroll
        for (int d4 = 0; d4 < 16; ++d4) {
            const float4 kt = Kt4[l][d4 ^ (l & 15)];
            const int g = d4 >> 2;
            #pragma unroll
            for (int i = 0; i < 4; ++i) {
                const float4 q4 = Qs4[w + 4 * i][d4];
                float s = dotp[i][g];
                s = fmaf(kt.x, q4.x, s);
                s = fmaf(kt.y, q4.y, s);
                s = fmaf(kt.z, q4.z, s);
                s = fmaf(kt.w, q4.w, s);
                dotp[i][g] = s;
            }
        }

        // ---- weights + f64 S-path updates (lane = m = m0+l)
        #pragma unroll
        for (int i = 0; i < 4; ++i) {
            const int r = w + 4 * i;
            const double lg = (((double)dotp[i][0] + (double)dotp[i][1]) +
                               ((double)dotp[i][2] + (double)dotp[i][3])) * 0.125;
            const double p64 = fast_exp64(lg);
            const double dx = (double)qc[r][0] - cmx;
            const double dy = (double)qc[r][1] - cmy;
            const double dz = (double)qc[r][2] - cmz;
            const double r2 = __fma_rn(dx, dx, __fma_rn(dy, dy, dz * dz));
            const double y0 = (double)rsqrtf((float)r2);
            const double y1 = y0 * __fma_rn(-0.5 * r2, y0 * y0, 1.5);
            const double dist = (r2 > 0.0) ? r2 * y1 : 0.0;   // sqrt via rsqrt+NR
            const double q64 = fast_exp64(dist * w4hd);
            pt[r][l] = (float)p64;
            qt[r][l] = (float)q64;
            sp[i]  += p64;
            sq[i]  += q64;
            spv[i] += p64 * Vm;
            sqv[i] += q64 * Vm;
        }
        __syncthreads();   // all waves done reading Kt4 (next stage safe)

        // ---- PV: lane = output dim l, rows w+4i; V direct from global,
        //      pt/qt wave-private LDS float4 broadcasts.
        const float* vbase = v + (bhN + m0) * HD_ + l;
        #pragma unroll 4
        for (int ml4 = 0; ml4 < 16; ++ml4) {
            float vt0 = vbase[(ml4 * 4 + 0) * HD_];
            float vt1 = vbase[(ml4 * 4 + 1) * HD_];
            float vt2 = vbase[(ml4 * 4 + 2) * HD_];
            float vt3 = vbase[(ml4 * 4 + 3) * HD_];
            #pragma unroll
            for (int i = 0; i < 4; ++i) {
                const float4 pp = *reinterpret_cast<const float4*>(&pt[w + 4 * i][ml4 * 4]);
                const float4 pq = *reinterpret_cast<const float4*>(&qt[w + 4 * i][ml4 * 4]);
                float ap = accp[i], aq = accq[i];
                ap = fmaf(pp.x, vt0, ap); aq = fmaf(pq.x, vt0, aq);
                ap = fmaf(pp.y, vt1, ap); aq = fmaf(pq.y, vt1, aq);
                ap = fmaf(pp.z, vt2, ap); aq = fmaf(pq.z, vt2, aq);
                ap = fmaf(pp.w, vt3, ap); aq = fmaf(pq.w, vt3, aq);
                accp[i] = ap; accq[i] = aq;
            }
        }
    }

    // ---- epilogue: f64 reduce, combine, normalize, store (lane = dim l)
    #pragma unroll
    for (int i = 0; i < 4; ++i) {
        double vsp = sp[i], vsq = sq[i], vspv = spv[i], vsqv = sqv[i];
        #pragma unroll
        for (int mm = 32; mm >= 1; mm >>= 1) {
            vsp  += __shfl_xor(vsp,  mm);
            vsq  += __shfl_xor(vsq,  mm);
            vspv += __shfl_xor(vspv, mm);
            vsqv += __shfl_xor(vsqv, mm);
        }
        const double w1 = (1.0 - ghd) / vsp;
        const double w2 = ghd / vsq;
        const double S  = w1 * vspv + w2 * vsqv;
        const double a  = w1 * (double)accp[i] + w2 * (double)accq[i];
        attn_out[((size_t)b * N_ + n0 + (w + 4 * i)) * C_ + h * HD_ + l] = (float)(a / S);
    }
}

// ---------------------------------------------------------------------------
extern "C" void kernel_launch(void* const* d_in, const int* in_sizes, int n_in,
                              void* d_out, int out_size, void* d_ws, size_t ws_size,
                              hipStream_t stream)
{
    const float* x      = (const float*)d_in[0];
    const float* coord  = (const float*)d_in[1];
    const float* W_qk   = (const float*)d_in[2];
    const float* W_v    = (const float*)d_in[3];
    const float* W_proj = (const float*)d_in[4];
    const float* b_proj = (const float*)d_in[5];
    const float* W_pos  = (const float*)d_in[6];
    // d_in[7] = b_pos (cancels in softmax), d_in[9] = pos_emb (cancels) — unused
    const float* gating = (const float*)d_in[8];

    float* ws   = (float*)d_ws;
    const size_t per = (size_t)B_ * H_ * N_ * HD_;   // 4,194,304 floats
    float*  qb   = ws;
    float*  kb   = qb + per;
    float*  vb   = kb + per;
    float*  attn = vb + per;
    double* wsh  = (double*)(attn + per);
    double* Vall = wsh + (size_t)H_ * C_;
    float*  out  = (float*)d_out;

    wsum_kernel<<<dim3(4, 16), 256, 0, stream>>>(W_v, wsh);
    vall_kernel<<<dim3(4, 16, 4), 256, 0, stream>>>(x, wsh, Vall);

    gemm_kernel<0><<<dim3(48, 32), 256, 0, stream>>>(
        x, W_qk, W_v, nullptr, qb, kb, vb, B_ * N_, 3 * C_, C_);

    attn_kernel<<<dim3(N_ / 16, H_, B_), 256, 0, stream>>>(
        qb, kb, vb, Vall, coord, W_pos, gating, attn);

    gemm_kernel<1><<<dim3(16, 32), 256, 0, stream>>>(
        attn, W_proj, nullptr, b_proj, out, nullptr, nullptr, B_ * N_, C_, C_);
}

// Round 7
// 1409.151 us; speedup vs baseline: 1.6542x; 1.1196x over previous
//
#include <hip/hip_runtime.h>
#include <math.h>

#define B_ 4
#define N_ 1024
#define C_ 1024
#define H_ 16
#define HD_ 64

// ---------------------------------------------------------------------------
// ERROR MODEL (validated r4/r6: absmax 16 vs threshold 97):
//   S = (1-g)*spv/sp + g*sqv/sq ~ 4e-5 from cancellation of O(3) weighted
//   means; budget delta_S ~1.3e-7 => weight rel err <= 4e-8 for BOTH
//   softmaxes (patch AND pos) -> f64 logits+exp mandatory (fast_exp64 3e-10).
//   V_m exact via f64 wsum collapse. q,k <1e-7 -> slab-f64 GEMM.
//   DAMPED paths (via W_proj, budget ~4e-3): v, PV numerators, proj GEMM
//   -> plain f32.
// PERF MODEL (r6 lesson): attn was 2-barrier/tile convoy-bound (VALU 52%).
// r7: double-buffer K + async-stage (issue loads early, LDS-write late),
// 1 barrier/tile. GEMMs split: f64-slab only where needed (q,k).
// ---------------------------------------------------------------------------

// fast f64 exp for |a| <= ~16: range-reduce + deg-8 Taylor. rel err ~3e-10.
__device__ __forceinline__ double fast_exp64(double a) {
    const double LOG2E = 1.4426950408889634074;
    const double LN2HI = 6.93147180369123816490e-01;
    const double LN2LO = 1.90821492927058770002e-10;
    const double MAGIC = 6755399441055744.0;   // 1.5 * 2^52
    double t     = a * LOG2E;
    double shift = t + MAGIC;
    int    n     = (int)__double_as_longlong(shift);
    double nd    = shift - MAGIC;
    double f     = __fma_rn(nd, -LN2HI, a);
    f            = __fma_rn(nd, -LN2LO, f);
    double p = 2.4801587301587301587e-05;
    p = __fma_rn(p, f, 1.9841269841269841270e-04);
    p = __fma_rn(p, f, 1.3888888888888888889e-03);
    p = __fma_rn(p, f, 8.3333333333333333333e-03);
    p = __fma_rn(p, f, 4.1666666666666666667e-02);
    p = __fma_rn(p, f, 1.6666666666666666667e-01);
    p = __fma_rn(p, f, 5.0e-01);
    p = __fma_rn(p, f, 1.0);
    p = __fma_rn(p, f, 1.0);
    return p * __longlong_as_double(((long long)(1023 + n)) << 52);
}

// ---------------------------------------------------------------------------
// Slab-compensated GEMM for q,k ONLY (O=2048). Tile 128x64, f32 slabs -> f64.
// ---------------------------------------------------------------------------
__global__ __launch_bounds__(256)
void gemm_qk_kernel(const float* __restrict__ A,
                    const float* __restrict__ W0,   // W_qk, rows 0..2047
                    float* __restrict__ outq,
                    float* __restrict__ outk,
                    int M, int K)
{
    __shared__ float As[16][132];
    __shared__ float Ws[16][68];

    const int t  = threadIdx.x;
    const int m0 = blockIdx.y * 128;
    const int o0 = blockIdx.x * 64;
    const int ty = t >> 4;
    const int tx = t & 15;

    double acc[8][4];
    #pragma unroll
    for (int i = 0; i < 8; ++i)
        #pragma unroll
        for (int j = 0; j < 4; ++j) acc[i][j] = 0.0;

    for (int k0 = 0; k0 < K; k0 += 16) {
        #pragma unroll
        for (int i = 0; i < 2; ++i) {
            int vix = t + i * 256;
            int r   = vix >> 2;
            int c4  = vix & 3;
            const float4 a4 = *reinterpret_cast<const float4*>(&A[(size_t)(m0 + r) * K + k0 + c4 * 4]);
            As[c4 * 4 + 0][r] = a4.x;
            As[c4 * 4 + 1][r] = a4.y;
            As[c4 * 4 + 2][r] = a4.z;
            As[c4 * 4 + 3][r] = a4.w;
        }
        {
            int c  = t >> 2;
            int c4 = t & 3;
            const float4 w4 = *reinterpret_cast<const float4*>(&W0[(size_t)(o0 + c) * K + k0 + c4 * 4]);
            Ws[c4 * 4 + 0][c] = w4.x;
            Ws[c4 * 4 + 1][c] = w4.y;
            Ws[c4 * 4 + 2][c] = w4.z;
            Ws[c4 * 4 + 3][c] = w4.w;
        }
        __syncthreads();

        float sacc[8][4];
        #pragma unroll
        for (int i = 0; i < 8; ++i)
            #pragma unroll
            for (int j = 0; j < 4; ++j) sacc[i][j] = 0.f;

        #pragma unroll
        for (int kk = 0; kk < 16; ++kk) {
            float a[8], bb[4];
            *reinterpret_cast<float4*>(&a[0])  = *reinterpret_cast<const float4*>(&As[kk][ty * 8]);
            *reinterpret_cast<float4*>(&a[4])  = *reinterpret_cast<const float4*>(&As[kk][ty * 8 + 4]);
            *reinterpret_cast<float4*>(&bb[0]) = *reinterpret_cast<const float4*>(&Ws[kk][tx * 4]);
            #pragma unroll
            for (int i = 0; i < 8; ++i)
                #pragma unroll
                for (int j = 0; j < 4; ++j)
                    sacc[i][j] += a[i] * bb[j];
        }
        #pragma unroll
        for (int i = 0; i < 8; ++i)
            #pragma unroll
            for (int j = 0; j < 4; ++j) acc[i][j] += (double)sacc[i][j];
        __syncthreads();
    }

    int oo = o0 + tx * 4;
    float* dst = (oo < 1024) ? outq : outk;
    oo &= 1023;
    const int hh = oo >> 6, d0 = oo & 63;
    #pragma unroll
    for (int i = 0; i < 8; ++i) {
        int m = m0 + ty * 8 + i;
        int bb_ = m >> 10, n = m & 1023;
        float4 r0 = make_float4((float)acc[i][0], (float)acc[i][1],
                                (float)acc[i][2], (float)acc[i][3]);
        *reinterpret_cast<float4*>(&dst[((((size_t)bb_ * H_) + hh) * N_ + n) * HD_ + d0]) = r0;
    }
}

// ---------------------------------------------------------------------------
// Plain f32 GEMM, tile 128x128, 8x8/thread (damped paths: v and proj).
// MODE 0: v scatter into [B][H][N][64]. MODE 1: row-major + bias.
// ---------------------------------------------------------------------------
template<int MODE>
__global__ __launch_bounds__(256)
void gemm128_kernel(const float* __restrict__ A,
                    const float* __restrict__ W0,
                    const float* __restrict__ bias,
                    float* __restrict__ out0,
                    int M, int O, int K)
{
    __shared__ float As[16][132];
    __shared__ float Ws[16][132];

    const int t  = threadIdx.x;
    const int m0 = blockIdx.y * 128;
    const int o0 = blockIdx.x * 128;
    const int ty = t >> 4;
    const int tx = t & 15;

    float acc[8][8];
    #pragma unroll
    for (int i = 0; i < 8; ++i)
        #pragma unroll
        for (int j = 0; j < 8; ++j) acc[i][j] = 0.f;

    for (int k0 = 0; k0 < K; k0 += 16) {
        #pragma unroll
        for (int i = 0; i < 2; ++i) {
            int vix = t + i * 256;
            int r   = vix >> 2;
            int c4  = vix & 3;
            const float4 a4 = *reinterpret_cast<const float4*>(&A[(size_t)(m0 + r) * K + k0 + c4 * 4]);
            As[c4 * 4 + 0][r] = a4.x;
            As[c4 * 4 + 1][r] = a4.y;
            As[c4 * 4 + 2][r] = a4.z;
            As[c4 * 4 + 3][r] = a4.w;
        }
        #pragma unroll
        for (int i = 0; i < 2; ++i) {
            int vix = t + i * 256;
            int c   = vix >> 2;
            int c4  = vix & 3;
            const float4 w4 = *reinterpret_cast<const float4*>(&W0[(size_t)(o0 + c) * K + k0 + c4 * 4]);
            Ws[c4 * 4 + 0][c] = w4.x;
            Ws[c4 * 4 + 1][c] = w4.y;
            Ws[c4 * 4 + 2][c] = w4.z;
            Ws[c4 * 4 + 3][c] = w4.w;
        }
        __syncthreads();

        #pragma unroll
        for (int kk = 0; kk < 16; ++kk) {
            float a[8], bb[8];
            *reinterpret_cast<float4*>(&a[0])  = *reinterpret_cast<const float4*>(&As[kk][ty * 8]);
            *reinterpret_cast<float4*>(&a[4])  = *reinterpret_cast<const float4*>(&As[kk][ty * 8 + 4]);
            *reinterpret_cast<float4*>(&bb[0]) = *reinterpret_cast<const float4*>(&Ws[kk][tx * 8]);
            *reinterpret_cast<float4*>(&bb[4]) = *reinterpret_cast<const float4*>(&Ws[kk][tx * 8 + 4]);
            #pragma unroll
            for (int i = 0; i < 8; ++i)
                #pragma unroll
                for (int j = 0; j < 8; ++j)
                    acc[i][j] += a[i] * bb[j];
        }
        __syncthreads();
    }

    if (MODE == 1) {
        float bs[8];
        *reinterpret_cast<float4*>(&bs[0]) = *reinterpret_cast<const float4*>(&bias[o0 + tx * 8]);
        *reinterpret_cast<float4*>(&bs[4]) = *reinterpret_cast<const float4*>(&bias[o0 + tx * 8 + 4]);
        #pragma unroll
        for (int i = 0; i < 8; ++i) {
            int m = m0 + ty * 8 + i;
            float* p = &out0[(size_t)m * O + o0 + tx * 8];
            float4 r0 = make_float4(acc[i][0] + bs[0], acc[i][1] + bs[1], acc[i][2] + bs[2], acc[i][3] + bs[3]);
            float4 r1 = make_float4(acc[i][4] + bs[4], acc[i][5] + bs[5], acc[i][6] + bs[6], acc[i][7] + bs[7]);
            *reinterpret_cast<float4*>(p)     = r0;
            *reinterpret_cast<float4*>(p + 4) = r1;
        }
    } else {
        int oo = o0 + tx * 8;              // 8-aligned, inside one head
        const int hh = oo >> 6, d0 = oo & 63;
        #pragma unroll
        for (int i = 0; i < 8; ++i) {
            int m = m0 + ty * 8 + i;
            int bb_ = m >> 10, n = m & 1023;
            float* p = &out0[((((size_t)bb_ * H_) + hh) * N_ + n) * HD_ + d0];
            *reinterpret_cast<float4*>(p)     = make_float4(acc[i][0], acc[i][1], acc[i][2], acc[i][3]);
            *reinterpret_cast<float4*>(p + 4) = make_float4(acc[i][4], acc[i][5], acc[i][6], acc[i][7]);
        }
    }
}

// ---------------------------------------------------------------------------
__global__ void wsum_kernel(const float* __restrict__ W_v, double* __restrict__ wsh)
{
    const int k = blockIdx.x * 256 + threadIdx.x;
    const int h = blockIdx.y;
    double s = 0.0;
    #pragma unroll 8
    for (int d = 0; d < 64; ++d) s += (double)W_v[(size_t)(h * 64 + d) * C_ + k];
    wsh[h * C_ + k] = s;
}

__global__ __launch_bounds__(256)
void vall_kernel(const float* __restrict__ x, const double* __restrict__ wsh,
                 double* __restrict__ Vall)
{
    __shared__ double ws_s[1024];
    const int h = blockIdx.y, b = blockIdx.z;
    const int m = blockIdx.x * 256 + threadIdx.x;
    for (int i = threadIdx.x; i < 1024; i += 256) ws_s[i] = wsh[h * C_ + i];
    __syncthreads();
    const float* xr = x + ((size_t)b * N_ + m) * C_;
    double acc = 0.0;
    #pragma unroll 8
    for (int kk = 0; kk < 1024; ++kk) acc += (double)xr[kk] * ws_s[kk];
    Vall[((size_t)b * H_ + h) * N_ + m] = acc;
}

// ---------------------------------------------------------------------------
// Fused attention r7: r6 numerics + double-buffered K + async staging.
// Per tile: (1) issue next K/Vm/coord global loads into regs,
// (2) QK from Kt4[cur], (3) f64 weights + S updates, (4) PV (V from global,
// pt/qt wave-private), (5) LDS-write staged regs to Kt4[nxt], (6) ONE barrier.
// ---------------------------------------------------------------------------
__global__ __launch_bounds__(256)
void attn_kernel(const float* __restrict__ q,
                 const float* __restrict__ k,
                 const float* __restrict__ v,
                 const double* __restrict__ Vall,   // [B][H][N]
                 const float* __restrict__ coord,   // [B][N][3]
                 const float* __restrict__ W_pos,   // [H][4]
                 const float* __restrict__ gating,  // [H]
                 float* __restrict__ attn_out)      // [B][N][C]
{
    __shared__ float4 Qs4[16][16];                 // 4KB
    __shared__ float4 Kt4[2][64][16];              // 32KB double-buffered K
    __shared__ __align__(16) float pt[16][64];     // 4KB (wave-private rows)
    __shared__ __align__(16) float qt[16][64];     // 4KB
    __shared__ float qc[16][3];

    const int t  = threadIdx.x;
    const int w  = t >> 6;     // wave 0..3, owns rows {w, w+4, w+8, w+12}
    const int l  = t & 63;
    const int n0 = blockIdx.x * 16;
    const int h  = blockIdx.y;
    const int b  = blockIdx.z;
    const size_t bhN = ((size_t)b * H_ + h) * N_;

    // staging index for this thread (4 vectors/tile)
    const int sr0 = t >> 4;          // rows t>>4, +16, +32, +48
    const int sc  = t & 15;

    Qs4[t >> 4][t & 15] = reinterpret_cast<const float4*>(q + (bhN + n0) * HD_)[t];
    if (t < 48) qc[t / 3][t % 3] = coord[((size_t)b * N_ + n0 + t / 3) * 3 + (t % 3)];
    const double w4hd = (double)W_pos[h * 4 + 3];
    const double ghd  = 1.0 / (1.0 + exp(-(double)gating[h]));

    double sp[4], sq[4], spv[4], sqv[4];
    float accp[4], accq[4];
    #pragma unroll
    for (int i = 0; i < 4; ++i) {
        sp[i] = 0.0; sq[i] = 0.0; spv[i] = 0.0; sqv[i] = 0.0;
        accp[i] = 0.f; accq[i] = 0.f;
    }

    // ---- prologue: stage tile 0 + its Vm/coord
    {
        const float4* kb4 = reinterpret_cast<const float4*>(k + bhN * HD_);
        #pragma unroll
        for (int i = 0; i < 4; ++i)
            Kt4[0][sr0 + i * 16][sc ^ ((sr0 + i * 16) & 15)] = kb4[t + i * 256];
    }
    double Vm  = Vall[bhN + l];
    double cmx = (double)coord[((size_t)b * N_ + l) * 3 + 0];
    double cmy = (double)coord[((size_t)b * N_ + l) * 3 + 1];
    double cmz = (double)coord[((size_t)b * N_ + l) * 3 + 2];
    __syncthreads();

    for (int t16 = 0; t16 < 16; ++t16) {
        const int cur = t16 & 1;
        const int m0  = t16 * 64;

        // ---- (1) issue next tile's loads (stay in flight through compute)
        float4 st0, st1, st2, st3;
        double VmN = 0.0, cmxN = 0.0, cmyN = 0.0, cmzN = 0.0;
        if (t16 < 15) {
            const float4* kb4 = reinterpret_cast<const float4*>(k + (bhN + m0 + 64) * HD_);
            st0 = kb4[t];
            st1 = kb4[t + 256];
            st2 = kb4[t + 512];
            st3 = kb4[t + 768];
            VmN  = Vall[bhN + m0 + 64 + l];
            cmxN = (double)coord[((size_t)b * N_ + m0 + 64 + l) * 3 + 0];
            cmyN = (double)coord[((size_t)b * N_ + m0 + 64 + l) * 3 + 1];
            cmzN = (double)coord[((size_t)b * N_ + m0 + 64 + l) * 3 + 2];
        }

        // ---- (2) QK^T logits from Kt4[cur]: rows w+4i, column m0+l
        float dotp[4][4];
        #pragma unroll
        for (int i = 0; i < 4; ++i)
            #pragma unroll
            for (int g = 0; g < 4; ++g) dotp[i][g] = 0.f;
        #pragma unroll
        for (int d4 = 0; d4 < 16; ++d4) {
            const float4 kt = Kt4[cur][l][d4 ^ (l & 15)];
            const int g = d4 >> 2;
            #pragma unroll
            for (int i = 0; i < 4; ++i) {
                const float4 q4 = Qs4[w + 4 * i][d4];
                float s = dotp[i][g];
                s = fmaf(kt.x, q4.x, s);
                s = fmaf(kt.y, q4.y, s);
                s = fmaf(kt.z, q4.z, s);
                s = fmaf(kt.w, q4.w, s);
                dotp[i][g] = s;
            }
        }

        // ---- (3) f64 weights + S-path updates (lane = m = m0+l)
        #pragma unroll
        for (int i = 0; i < 4; ++i) {
            const int r = w + 4 * i;
            const double lg = (((double)dotp[i][0] + (double)dotp[i][1]) +
                               ((double)dotp[i][2] + (double)dotp[i][3])) * 0.125;
            const double p64 = fast_exp64(lg);
            const double dx = (double)qc[r][0] - cmx;
            const double dy = (double)qc[r][1] - cmy;
            const double dz = (double)qc[r][2] - cmz;
            const double r2 = __fma_rn(dx, dx, __fma_rn(dy, dy, dz * dz));
            const double y0 = (double)rsqrtf((float)r2);
            const double y1 = y0 * __fma_rn(-0.5 * r2, y0 * y0, 1.5);
            const double dist = (r2 > 0.0) ? r2 * y1 : 0.0;
            const double q64 = fast_exp64(dist * w4hd);
            pt[r][l] = (float)p64;
            qt[r][l] = (float)q64;
            sp[i]  += p64;
            sq[i]  += q64;
            spv[i] += p64 * Vm;
            sqv[i] += q64 * Vm;
        }

        // ---- (4) PV: lane = output dim l; V direct from global
        const float* vbase = v + (bhN + m0) * HD_ + l;
        #pragma unroll 4
        for (int ml4 = 0; ml4 < 16; ++ml4) {
            float vt0 = vbase[(ml4 * 4 + 0) * HD_];
            float vt1 = vbase[(ml4 * 4 + 1) * HD_];
            float vt2 = vbase[(ml4 * 4 + 2) * HD_];
            float vt3 = vbase[(ml4 * 4 + 3) * HD_];
            #pragma unroll
            for (int i = 0; i < 4; ++i) {
                const float4 pp = *reinterpret_cast<const float4*>(&pt[w + 4 * i][ml4 * 4]);
                const float4 pq = *reinterpret_cast<const float4*>(&qt[w + 4 * i][ml4 * 4]);
                float ap = accp[i], aq = accq[i];
                ap = fmaf(pp.x, vt0, ap); aq = fmaf(pq.x, vt0, aq);
                ap = fmaf(pp.y, vt1, ap); aq = fmaf(pq.y, vt1, aq);
                ap = fmaf(pp.z, vt2, ap); aq = fmaf(pq.z, vt2, aq);
                ap = fmaf(pp.w, vt3, ap); aq = fmaf(pq.w, vt3, aq);
                accp[i] = ap; accq[i] = aq;
            }
        }

        // ---- (5) write staged K regs into the other buffer; roll Vm/coord
        if (t16 < 15) {
            const int nxt = cur ^ 1;
            Kt4[nxt][sr0     ][sc ^ ( sr0       & 15)] = st0;
            Kt4[nxt][sr0 + 16][sc ^ ((sr0 + 16) & 15)] = st1;
            Kt4[nxt][sr0 + 32][sc ^ ((sr0 + 32) & 15)] = st2;
            Kt4[nxt][sr0 + 48][sc ^ ((sr0 + 48) & 15)] = st3;
            Vm = VmN; cmx = cmxN; cmy = cmyN; cmz = cmzN;
        }
        // ---- (6) single barrier: Kt4[nxt] complete, Kt4[cur] free
        __syncthreads();
    }

    // ---- epilogue: f64 reduce, combine, normalize, store (lane = dim l)
    #pragma unroll
    for (int i = 0; i < 4; ++i) {
        double vsp = sp[i], vsq = sq[i], vspv = spv[i], vsqv = sqv[i];
        #pragma unroll
        for (int mm = 32; mm >= 1; mm >>= 1) {
            vsp  += __shfl_xor(vsp,  mm);
            vsq  += __shfl_xor(vsq,  mm);
            vspv += __shfl_xor(vspv, mm);
            vsqv += __shfl_xor(vsqv, mm);
        }
        const double w1 = (1.0 - ghd) / vsp;
        const double w2 = ghd / vsq;
        const double S  = w1 * vspv + w2 * vsqv;
        const double a  = w1 * (double)accp[i] + w2 * (double)accq[i];
        attn_out[((size_t)b * N_ + n0 + (w + 4 * i)) * C_ + h * HD_ + l] = (float)(a / S);
    }
}

// ---------------------------------------------------------------------------
extern "C" void kernel_launch(void* const* d_in, const int* in_sizes, int n_in,
                              void* d_out, int out_size, void* d_ws, size_t ws_size,
                              hipStream_t stream)
{
    const float* x      = (const float*)d_in[0];
    const float* coord  = (const float*)d_in[1];
    const float* W_qk   = (const float*)d_in[2];
    const float* W_v    = (const float*)d_in[3];
    const float* W_proj = (const float*)d_in[4];
    const float* b_proj = (const float*)d_in[5];
    const float* W_pos  = (const float*)d_in[6];
    // d_in[7] = b_pos (cancels in softmax), d_in[9] = pos_emb (cancels) — unused
    const float* gating = (const float*)d_in[8];

    float* ws   = (float*)d_ws;
    const size_t per = (size_t)B_ * H_ * N_ * HD_;   // 4,194,304 floats
    float*  qb   = ws;
    float*  kb   = qb + per;
    float*  vb   = kb + per;
    float*  attn = vb + per;
    double* wsh  = (double*)(attn + per);
    double* Vall = wsh + (size_t)H_ * C_;
    float*  out  = (float*)d_out;

    // exact S-path precomputation
    wsum_kernel<<<dim3(4, 16), 256, 0, stream>>>(W_v, wsh);
    vall_kernel<<<dim3(4, 16, 4), 256, 0, stream>>>(x, wsh, Vall);

    // q,k: slab-f64 GEMM (logit path). v: plain f32 (damped).
    gemm_qk_kernel<<<dim3(32, 32), 256, 0, stream>>>(x, W_qk, qb, kb, B_ * N_, C_);
    gemm128_kernel<0><<<dim3(8, 32), 256, 0, stream>>>(x, W_v, nullptr, vb, B_ * N_, C_, C_);

    attn_kernel<<<dim3(N_ / 16, H_, B_), 256, 0, stream>>>(
        qb, kb, vb, Vall, coord, W_pos, gating, attn);

    // proj: plain f32 (damped)
    gemm128_kernel<1><<<dim3(8, 32), 256, 0, stream>>>(
        attn, W_proj, b_proj, out, B_ * N_, C_, C_);
}